// Round 3
// baseline (27742.630 us; speedup 1.0000x reference)
//
#include <hip/hip_runtime.h>

#define H 64
#define G4 256  // 4*H

typedef float v2f __attribute__((ext_vector_type(2)));

__device__ __forceinline__ float sigmoid_f(float x) {
  return 1.f / (1.f + __expf(-x));
}
__device__ __forceinline__ float tanh_f(float x) {
  float e = __expf(2.f * x);
  return 1.f - 2.f / (e + 1.f);
}

// Workgroup barrier draining ONLY lgkmcnt (LDS). Global loads/stores stay in
// flight across it; compiler still inserts vmcnt waits at actual uses.
__device__ __forceinline__ void wg_barrier() {
  asm volatile("s_waitcnt lgkmcnt(0)\n\ts_barrier" ::: "memory");
}

// xw[t][j] = x[t][0]*W[0][j] + x[t][1]*W[1][j] + b[j]
__global__ __launch_bounds__(G4) void proj_x(const float* __restrict__ x,
                                             const float* __restrict__ W,
                                             const float* __restrict__ b,
                                             float* __restrict__ xw) {
  const int t = blockIdx.x;
  const int j = threadIdx.x;
  const float x0 = x[2 * t];
  const float x1 = x[2 * t + 1];
  xw[(size_t)t * G4 + j] = fmaf(x0, W[j], fmaf(x1, W[G4 + j], b[j]));
}

// Fused 3-layer systolic LSTM scan. 768 threads = 3 layer-groups x 256.
// Layer L processes timestep t = s - L at global step s. Inter-layer h flows
// through LDS; layers 2,3 compute their input projection (h_prev @ W) inline.
__global__ __launch_bounds__(768, 3) void fused_scan(
    const float* __restrict__ xw,  // [T,256] precomputed x@W1+b1
    const float* __restrict__ U1,
    const float* __restrict__ W2, const float* __restrict__ U2,
    const float* __restrict__ b2,
    const float* __restrict__ W3, const float* __restrict__ U3,
    const float* __restrict__ b3,
    float* __restrict__ h3out, int T) {
  __shared__ float sh_h[3 * H];   // current h per layer
  __shared__ float sh_a[3 * G4];  // gate activations per layer
  const int tid = (int)threadIdx.x;
  const int L = tid >> 8;    // layer 0..2 (4 waves each -> wave-uniform)
  const int j = tid & 255;   // gate column

  // Recurrent matrix column j -> registers (paired for packed fma)
  const float* Umat = (L == 0) ? U1 : ((L == 1) ? U2 : U3);
  v2f u2[H / 2];
#pragma unroll
  for (int k = 0; k < H / 2; ++k) {
    u2[k][0] = Umat[(2 * k) * G4 + j];
    u2[k][1] = Umat[(2 * k + 1) * G4 + j];
  }
  // Input-projection matrix column (layers 1,2 only) + bias
  v2f w2[H / 2];
  float bj = 0.f;
  if (L > 0) {
    const float* Wmat = (L == 1) ? W2 : W3;
#pragma unroll
    for (int k = 0; k < H / 2; ++k) {
      w2[k][0] = Wmat[(2 * k) * G4 + j];
      w2[k][1] = Wmat[(2 * k + 1) * G4 + j];
    }
    bj = (L == 1) ? b2[j] : b3[j];
  }

  float c = 0.f;
  if (tid < 3 * H) sh_h[tid] = 0.f;
  wg_barrier();

  const bool is_sig = (j < 2 * H) || (j >= 3 * H);  // wave-uniform

  float nxt = 0.f;
  if (L == 0) nxt = xw[j];  // 1-step-ahead xw prefetch register

  const int S = T + 2;
  for (int s = 0; s < S; ++s) {
    const int t = s - L;
    const bool active = (t >= 0) && (t < T);  // uniform within layer group

    if (active) {
      v2f a0, a1, a2, a3;
      if (L == 0) {
        a0 = (v2f){nxt, 0.f};
        a1 = (v2f){0.f, 0.f};
        const int sn = (s + 1 < T) ? (s + 1) : (T - 1);
        nxt = xw[(size_t)sn * G4 + j];  // fire prefetch; lands next step
        const float4* h4 = (const float4*)sh_h;  // layer 0 own h
#pragma unroll
        for (int kk = 0; kk < H / 4; ++kk) {
          float4 hv = h4[kk];
          v2f hlo = {hv.x, hv.y}, hhi = {hv.z, hv.w};
          a0 = __builtin_elementwise_fma(hlo, u2[2 * kk], a0);
          a1 = __builtin_elementwise_fma(hhi, u2[2 * kk + 1], a1);
        }
        a2 = (v2f){0.f, 0.f};
        a3 = (v2f){0.f, 0.f};
      } else {
        a0 = (v2f){bj, 0.f};
        a1 = (v2f){0.f, 0.f};
        a2 = (v2f){0.f, 0.f};
        a3 = (v2f){0.f, 0.f};
        const float4* hown = (const float4*)(sh_h + L * H);
        const float4* hprv = (const float4*)(sh_h + (L - 1) * H);
#pragma unroll
        for (int kk = 0; kk < H / 4; ++kk) {
          float4 ho = hown[kk];
          float4 hp = hprv[kk];
          v2f olo = {ho.x, ho.y}, ohi = {ho.z, ho.w};
          v2f plo = {hp.x, hp.y}, phi = {hp.z, hp.w};
          a0 = __builtin_elementwise_fma(olo, u2[2 * kk], a0);
          a1 = __builtin_elementwise_fma(ohi, u2[2 * kk + 1], a1);
          a2 = __builtin_elementwise_fma(plo, w2[2 * kk], a2);
          a3 = __builtin_elementwise_fma(phi, w2[2 * kk + 1], a3);
        }
      }
      v2f sv = (a0 + a1) + (a2 + a3);
      const float acc = sv[0] + sv[1];
      sh_a[(L << 8) + j] = is_sig ? sigmoid_f(acc) : tanh_f(acc);
    }
    wg_barrier();

    if (active && j < H) {
      const int base = L << 8;
      const float gi = sh_a[base + j];
      const float gf = sh_a[base + j + H];
      const float gg = sh_a[base + j + 2 * H];
      const float go = sh_a[base + j + 3 * H];
      c = fmaf(gf, c, gi * gg);
      const float h = go * tanh_f(c);
      sh_h[L * H + j] = h;
      if (L == 2 && t == T - 1) h3out[j] = h;  // only global write of the scan
    }
    wg_barrier();
  }
}

// Dense head: relu(h3@Wd1+bd1) -> relu(@Wd2+bd2) -> @Wl+bl
__global__ __launch_bounds__(64) void head_k(const float* __restrict__ hlast,
                                             const float* __restrict__ Wd1,
                                             const float* __restrict__ bd1,
                                             const float* __restrict__ Wd2,
                                             const float* __restrict__ bd2,
                                             const float* __restrict__ Wl,
                                             const float* __restrict__ bl,
                                             float* __restrict__ out) {
  __shared__ float s_h[H];
  __shared__ float s_a[20];
  __shared__ float s_b[20];
  const int j = threadIdx.x;
  s_h[j] = hlast[j];
  __syncthreads();
  if (j < 20) {
    float acc = bd1[j];
#pragma unroll
    for (int k = 0; k < H; ++k) acc = fmaf(s_h[k], Wd1[k * 20 + j], acc);
    s_a[j] = fmaxf(acc, 0.f);
  }
  __syncthreads();
  if (j < 20) {
    float acc = bd2[j];
#pragma unroll
    for (int k = 0; k < 20; ++k) acc = fmaf(s_a[k], Wd2[k * 20 + j], acc);
    s_b[j] = fmaxf(acc, 0.f);
  }
  __syncthreads();
  if (j < 10) {
    float acc = bl[j];
#pragma unroll
    for (int k = 0; k < 20; ++k) acc = fmaf(s_b[k], Wl[k * 10 + j], acc);
    out[j] = acc;
  }
}

extern "C" void kernel_launch(void* const* d_in, const int* in_sizes, int n_in,
                              void* d_out, int out_size, void* d_ws, size_t ws_size,
                              hipStream_t stream) {
  const float* x   = (const float*)d_in[0];
  const float* W1  = (const float*)d_in[1];
  const float* U1  = (const float*)d_in[2];
  const float* b1  = (const float*)d_in[3];
  const float* W2  = (const float*)d_in[4];
  const float* U2  = (const float*)d_in[5];
  const float* b2  = (const float*)d_in[6];
  const float* W3  = (const float*)d_in[7];
  const float* U3  = (const float*)d_in[8];
  const float* b3  = (const float*)d_in[9];
  const float* Wd1 = (const float*)d_in[10];
  const float* bd1 = (const float*)d_in[11];
  const float* Wd2 = (const float*)d_in[12];
  const float* bd2 = (const float*)d_in[13];
  const float* Wl  = (const float*)d_in[14];
  const float* bl  = (const float*)d_in[15];
  const int T = in_sizes[0] / 2;  // 16384

  // workspace: xw [T,256] | h3 [64]
  float* xw = (float*)d_ws;
  float* h3 = xw + (size_t)T * G4;

  proj_x<<<T, G4, 0, stream>>>(x, W1, b1, xw);
  fused_scan<<<1, 768, 0, stream>>>(xw, U1, W2, U2, b2, W3, U3, b3, h3, T);
  head_k<<<1, 64, 0, stream>>>(h3, Wd1, bd1, Wd2, bd2, Wl, bl, (float*)d_out);
}

// Round 4
// 25749.261 us; speedup vs baseline: 1.0774x; 1.0774x over previous
//
#include <hip/hip_runtime.h>

#define H 64
#define G4 256  // 4*H

typedef float v2f __attribute__((ext_vector_type(2)));

__device__ __forceinline__ float sigmoid_f(float x) {
  return 1.f / (1.f + __expf(-x));
}
__device__ __forceinline__ float tanh_f(float x) {
  float e = __expf(2.f * x);
  return 1.f - 2.f / (e + 1.f);
}

// Workgroup barrier draining ONLY lgkmcnt (LDS). Global loads/stores stay in
// flight across it; compiler still inserts vmcnt waits at actual uses.
__device__ __forceinline__ void wg_barrier() {
  asm volatile("s_waitcnt lgkmcnt(0)\n\ts_barrier" ::: "memory");
}

// xw[t][j] = x[t][0]*W[0][j] + x[t][1]*W[1][j] + b[j]
__global__ __launch_bounds__(G4) void proj_x(const float* __restrict__ x,
                                             const float* __restrict__ W,
                                             const float* __restrict__ b,
                                             float* __restrict__ xw) {
  const int t = blockIdx.x;
  const int j = threadIdx.x;
  const float x0 = x[2 * t];
  const float x1 = x[2 * t + 1];
  xw[(size_t)t * G4 + j] = fmaf(x0, W[j], fmaf(x1, W[G4 + j], b[j]));
}

// Fused 3-layer systolic LSTM scan. 768 threads = 3 layer-groups x 256.
// Layer L processes timestep t = s - L at global step s. Inter-layer h flows
// through LDS; layers 2,3 compute their input projection (h_prev @ W) inline.
// NOTE: one-arg launch_bounds only — hardware cap for 12 waves (3/SIMD) is
// ~170 VGPR/wave; u2+w2 (128 floats) must stay register-resident. A forced
// occupancy hint here previously capped VGPRs at 84 and spilled w2 into the
// recurrence critical path (4x regression).
__global__ __launch_bounds__(768) void fused_scan(
    const float* __restrict__ xw,  // [T,256] precomputed x@W1+b1
    const float* __restrict__ U1,
    const float* __restrict__ W2, const float* __restrict__ U2,
    const float* __restrict__ b2,
    const float* __restrict__ W3, const float* __restrict__ U3,
    const float* __restrict__ b3,
    float* __restrict__ h3out, int T) {
  __shared__ float sh_h[3 * H];   // current h per layer
  __shared__ float sh_a[3 * G4];  // gate activations per layer
  const int tid = (int)threadIdx.x;
  const int L = tid >> 8;    // layer 0..2 (4 waves each -> wave-uniform)
  const int j = tid & 255;   // gate column

  // Recurrent matrix column j -> registers (paired for packed fma).
  const float* Umat = (L == 0) ? U1 : ((L == 1) ? U2 : U3);
  // Input-projection column: UNCONDITIONAL init for uniform register demand
  // (L0 loads a dummy column from U1 and never uses it).
  const float* Wmat = (L == 0) ? U1 : ((L == 1) ? W2 : W3);

  v2f u2[H / 2];
#pragma unroll
  for (int k = 0; k < H / 2; ++k) {
    u2[k][0] = Umat[(2 * k) * G4 + j];
    u2[k][1] = Umat[(2 * k + 1) * G4 + j];
  }
  v2f w2[H / 2];
#pragma unroll
  for (int k = 0; k < H / 2; ++k) {
    w2[k][0] = Wmat[(2 * k) * G4 + j];
    w2[k][1] = Wmat[(2 * k + 1) * G4 + j];
  }
  float bj = 0.f;
  if (L == 1) bj = b2[j];
  if (L == 2) bj = b3[j];

  float c = 0.f;
  if (tid < 3 * H) sh_h[tid] = 0.f;
  wg_barrier();

  const bool is_sig = (j < 2 * H) || (j >= 3 * H);  // wave-uniform

  float nxt = 0.f;
  if (L == 0) nxt = xw[j];  // 1-step-ahead xw prefetch register

  const int S = T + 2;
  for (int s = 0; s < S; ++s) {
    const int t = s - L;
    const bool active = (t >= 0) && (t < T);  // uniform within layer group

    if (active) {
      v2f a0, a1, a2, a3;
      if (L == 0) {
        a0 = (v2f){nxt, 0.f};
        a1 = (v2f){0.f, 0.f};
        const int sn = (s + 1 < T) ? (s + 1) : (T - 1);
        nxt = xw[(size_t)sn * G4 + j];  // fire prefetch; lands next step
        const float4* h4 = (const float4*)sh_h;  // layer 0 own h
#pragma unroll
        for (int kk = 0; kk < H / 4; ++kk) {
          float4 hv = h4[kk];
          v2f hlo = {hv.x, hv.y}, hhi = {hv.z, hv.w};
          a0 = __builtin_elementwise_fma(hlo, u2[2 * kk], a0);
          a1 = __builtin_elementwise_fma(hhi, u2[2 * kk + 1], a1);
        }
        a2 = (v2f){0.f, 0.f};
        a3 = (v2f){0.f, 0.f};
      } else {
        a0 = (v2f){bj, 0.f};
        a1 = (v2f){0.f, 0.f};
        a2 = (v2f){0.f, 0.f};
        a3 = (v2f){0.f, 0.f};
        const float4* hown = (const float4*)(sh_h + L * H);
        const float4* hprv = (const float4*)(sh_h + (L - 1) * H);
#pragma unroll
        for (int kk = 0; kk < H / 4; ++kk) {
          float4 ho = hown[kk];
          float4 hp = hprv[kk];
          v2f olo = {ho.x, ho.y}, ohi = {ho.z, ho.w};
          v2f plo = {hp.x, hp.y}, phi = {hp.z, hp.w};
          a0 = __builtin_elementwise_fma(olo, u2[2 * kk], a0);
          a1 = __builtin_elementwise_fma(ohi, u2[2 * kk + 1], a1);
          a2 = __builtin_elementwise_fma(plo, w2[2 * kk], a2);
          a3 = __builtin_elementwise_fma(phi, w2[2 * kk + 1], a3);
        }
      }
      v2f sv = (a0 + a1) + (a2 + a3);
      const float acc = sv[0] + sv[1];
      sh_a[(L << 8) + j] = is_sig ? sigmoid_f(acc) : tanh_f(acc);
    }
    wg_barrier();

    if (active && j < H) {
      const int base = L << 8;
      const float gi = sh_a[base + j];
      const float gf = sh_a[base + j + H];
      const float gg = sh_a[base + j + 2 * H];
      const float go = sh_a[base + j + 3 * H];
      c = fmaf(gf, c, gi * gg);
      const float h = go * tanh_f(c);
      sh_h[L * H + j] = h;
      if (L == 2 && t == T - 1) h3out[j] = h;  // only global write of the scan
    }
    wg_barrier();
  }
}

// Dense head: relu(h3@Wd1+bd1) -> relu(@Wd2+bd2) -> @Wl+bl
__global__ __launch_bounds__(64) void head_k(const float* __restrict__ hlast,
                                             const float* __restrict__ Wd1,
                                             const float* __restrict__ bd1,
                                             const float* __restrict__ Wd2,
                                             const float* __restrict__ bd2,
                                             const float* __restrict__ Wl,
                                             const float* __restrict__ bl,
                                             float* __restrict__ out) {
  __shared__ float s_h[H];
  __shared__ float s_a[20];
  __shared__ float s_b[20];
  const int j = threadIdx.x;
  s_h[j] = hlast[j];
  __syncthreads();
  if (j < 20) {
    float acc = bd1[j];
#pragma unroll
    for (int k = 0; k < H; ++k) acc = fmaf(s_h[k], Wd1[k * 20 + j], acc);
    s_a[j] = fmaxf(acc, 0.f);
  }
  __syncthreads();
  if (j < 20) {
    float acc = bd2[j];
#pragma unroll
    for (int k = 0; k < 20; ++k) acc = fmaf(s_a[k], Wd2[k * 20 + j], acc);
    s_b[j] = fmaxf(acc, 0.f);
  }
  __syncthreads();
  if (j < 10) {
    float acc = bl[j];
#pragma unroll
    for (int k = 0; k < 20; ++k) acc = fmaf(s_b[k], Wl[k * 10 + j], acc);
    out[j] = acc;
  }
}

extern "C" void kernel_launch(void* const* d_in, const int* in_sizes, int n_in,
                              void* d_out, int out_size, void* d_ws, size_t ws_size,
                              hipStream_t stream) {
  const float* x   = (const float*)d_in[0];
  const float* W1  = (const float*)d_in[1];
  const float* U1  = (const float*)d_in[2];
  const float* b1  = (const float*)d_in[3];
  const float* W2  = (const float*)d_in[4];
  const float* U2  = (const float*)d_in[5];
  const float* b2  = (const float*)d_in[6];
  const float* W3  = (const float*)d_in[7];
  const float* U3  = (const float*)d_in[8];
  const float* b3  = (const float*)d_in[9];
  const float* Wd1 = (const float*)d_in[10];
  const float* bd1 = (const float*)d_in[11];
  const float* Wd2 = (const float*)d_in[12];
  const float* bd2 = (const float*)d_in[13];
  const float* Wl  = (const float*)d_in[14];
  const float* bl  = (const float*)d_in[15];
  const int T = in_sizes[0] / 2;  // 16384

  // workspace: xw [T,256] | h3 [64]
  float* xw = (float*)d_ws;
  float* h3 = xw + (size_t)T * G4;

  proj_x<<<T, G4, 0, stream>>>(x, W1, b1, xw);
  fused_scan<<<1, 768, 0, stream>>>(xw, U1, W2, U2, b2, W3, U3, b3, h3, T);
  head_k<<<1, 64, 0, stream>>>(h3, Wd1, bd1, Wd2, bd2, Wl, bl, (float*)d_out);
}

// Round 5
// 25739.127 us; speedup vs baseline: 1.0778x; 1.0004x over previous
//
#include <hip/hip_runtime.h>

#define H 64
#define G4 256  // 4*H

typedef float v2f __attribute__((ext_vector_type(2)));

__device__ __forceinline__ float sigmoid_f(float x) {
  return 1.f / (1.f + __expf(-x));
}
__device__ __forceinline__ float tanh_f(float x) {
  float e = __expf(2.f * x);
  return 1.f - 2.f / (e + 1.f);
}

// Workgroup barrier draining ONLY lgkmcnt (LDS). Global loads/stores stay in
// flight across it; compiler still inserts vmcnt waits at actual uses.
__device__ __forceinline__ void wg_barrier() {
  asm volatile("s_waitcnt lgkmcnt(0)\n\ts_barrier" ::: "memory");
}

// xw[t][j] = x[t][0]*W[0][j] + x[t][1]*W[1][j] + b[j]
__global__ __launch_bounds__(G4) void proj_x(const float* __restrict__ x,
                                             const float* __restrict__ W,
                                             const float* __restrict__ b,
                                             float* __restrict__ xw) {
  const int t = blockIdx.x;
  const int j = threadIdx.x;
  const float x0 = x[2 * t];
  const float x1 = x[2 * t + 1];
  xw[(size_t)t * G4 + j] = fmaf(x0, W[j], fmaf(x1, W[G4 + j], b[j]));
}

// Fused 3-layer systolic LSTM scan. 768 threads = 3 layer-groups x 256.
// Layer L processes timestep t = s - L at global step s. Inter-layer h flows
// through LDS; layers 2,3 compute their input projection (h_prev @ W) inline.
//
// REGISTER RESIDENCY IS THE WHOLE GAME here: 128 weight floats/thread must
// live in VGPRs. Two mechanisms, both required:
//  (a) amdgpu_waves_per_eu(3,3): pins scheduler+RA occupancy target to the
//      workgroup's own residency (12 waves / 4 SIMDs), budget 512/3 = 168
//      VGPRs. Without it the scheduler targets 6 waves/EU (VGPR=84) and
//      sinks the weight loads into the loop -> ~200cy L1 reload chains per
//      step (rounds 2-4 all hit this).
//  (b) opaque "+v" asm after the loads: the loop then consumes an asm
//      output, which cannot be rematerialized, so sinking is impossible.
__global__ __attribute__((amdgpu_flat_work_group_size(768, 768),
                          amdgpu_waves_per_eu(3, 3)))
void fused_scan(
    const float* __restrict__ xw,  // [T,256] precomputed x@W1+b1
    const float* __restrict__ U1,
    const float* __restrict__ W2, const float* __restrict__ U2,
    const float* __restrict__ b2,
    const float* __restrict__ W3, const float* __restrict__ U3,
    const float* __restrict__ b3,
    float* __restrict__ h3out, int T) {
  __shared__ float sh_h[3 * H];   // current h per layer
  __shared__ float sh_a[3 * G4];  // gate activations per layer
  const int tid = (int)threadIdx.x;
  const int L = tid >> 8;    // layer 0..2 (4 waves each -> wave-uniform)
  const int j = tid & 255;   // gate column

  const float* Umat = (L == 0) ? U1 : ((L == 1) ? U2 : U3);
  // L0 loads a dummy W column (allocation is kernel-wide max anyway).
  const float* Wmat = (L == 0) ? U1 : ((L == 1) ? W2 : W3);

  v2f u2[H / 2];
#pragma unroll
  for (int k = 0; k < H / 2; ++k) {
    u2[k][0] = Umat[(2 * k) * G4 + j];
    u2[k][1] = Umat[(2 * k + 1) * G4 + j];
  }
  v2f w2[H / 2];
#pragma unroll
  for (int k = 0; k < H / 2; ++k) {
    w2[k][0] = Wmat[(2 * k) * G4 + j];
    w2[k][1] = Wmat[(2 * k + 1) * G4 + j];
  }
  // Keep-alive: force every weight into a VGPR; uses below consume the asm
  // result so the loads cannot be sunk into the loop.
#pragma unroll
  for (int k = 0; k < H / 2; ++k) asm volatile("" : "+v"(u2[k]));
#pragma unroll
  for (int k = 0; k < H / 2; ++k) asm volatile("" : "+v"(w2[k]));

  float bj = 0.f;
  if (L == 1) bj = b2[j];
  if (L == 2) bj = b3[j];

  float c = 0.f;
  if (tid < 3 * H) sh_h[tid] = 0.f;
  wg_barrier();

  const bool is_sig = (j < 2 * H) || (j >= 3 * H);  // wave-uniform

  float nxt = 0.f;
  if (L == 0) nxt = xw[j];  // 1-step-ahead xw prefetch register

  const int S = T + 2;
  for (int s = 0; s < S; ++s) {
    const int t = s - L;
    const bool active = (t >= 0) && (t < T);  // uniform within layer group

    if (active) {
      v2f a0, a1, a2, a3;
      if (L == 0) {
        a0 = (v2f){nxt, 0.f};
        a1 = (v2f){0.f, 0.f};
        const int sn = (s + 1 < T) ? (s + 1) : (T - 1);
        nxt = xw[(size_t)sn * G4 + j];  // fire prefetch; lands next step
        const float4* h4 = (const float4*)sh_h;  // layer 0 own h
#pragma unroll
        for (int kk = 0; kk < H / 4; ++kk) {
          float4 hv = h4[kk];
          v2f hlo = {hv.x, hv.y}, hhi = {hv.z, hv.w};
          a0 = __builtin_elementwise_fma(hlo, u2[2 * kk], a0);
          a1 = __builtin_elementwise_fma(hhi, u2[2 * kk + 1], a1);
        }
        a2 = (v2f){0.f, 0.f};
        a3 = (v2f){0.f, 0.f};
      } else {
        a0 = (v2f){bj, 0.f};
        a1 = (v2f){0.f, 0.f};
        a2 = (v2f){0.f, 0.f};
        a3 = (v2f){0.f, 0.f};
        const float4* hown = (const float4*)(sh_h + L * H);
        const float4* hprv = (const float4*)(sh_h + (L - 1) * H);
#pragma unroll
        for (int kk = 0; kk < H / 4; ++kk) {
          float4 ho = hown[kk];
          float4 hp = hprv[kk];
          v2f olo = {ho.x, ho.y}, ohi = {ho.z, ho.w};
          v2f plo = {hp.x, hp.y}, phi = {hp.z, hp.w};
          a0 = __builtin_elementwise_fma(olo, u2[2 * kk], a0);
          a1 = __builtin_elementwise_fma(ohi, u2[2 * kk + 1], a1);
          a2 = __builtin_elementwise_fma(plo, w2[2 * kk], a2);
          a3 = __builtin_elementwise_fma(phi, w2[2 * kk + 1], a3);
        }
      }
      v2f sv = (a0 + a1) + (a2 + a3);
      const float acc = sv[0] + sv[1];
      sh_a[(L << 8) + j] = is_sig ? sigmoid_f(acc) : tanh_f(acc);
    }
    wg_barrier();

    if (active && j < H) {
      const int base = L << 8;
      const float gi = sh_a[base + j];
      const float gf = sh_a[base + j + H];
      const float gg = sh_a[base + j + 2 * H];
      const float go = sh_a[base + j + 3 * H];
      c = fmaf(gf, c, gi * gg);
      const float h = go * tanh_f(c);
      sh_h[L * H + j] = h;
      if (L == 2 && t == T - 1) h3out[j] = h;  // only global write of the scan
    }
    wg_barrier();
  }
}

// Dense head: relu(h3@Wd1+bd1) -> relu(@Wd2+bd2) -> @Wl+bl
__global__ __launch_bounds__(64) void head_k(const float* __restrict__ hlast,
                                             const float* __restrict__ Wd1,
                                             const float* __restrict__ bd1,
                                             const float* __restrict__ Wd2,
                                             const float* __restrict__ bd2,
                                             const float* __restrict__ Wl,
                                             const float* __restrict__ bl,
                                             float* __restrict__ out) {
  __shared__ float s_h[H];
  __shared__ float s_a[20];
  __shared__ float s_b[20];
  const int j = threadIdx.x;
  s_h[j] = hlast[j];
  __syncthreads();
  if (j < 20) {
    float acc = bd1[j];
#pragma unroll
    for (int k = 0; k < H; ++k) acc = fmaf(s_h[k], Wd1[k * 20 + j], acc);
    s_a[j] = fmaxf(acc, 0.f);
  }
  __syncthreads();
  if (j < 20) {
    float acc = bd2[j];
#pragma unroll
    for (int k = 0; k < 20; ++k) acc = fmaf(s_a[k], Wd2[k * 20 + j], acc);
    s_b[j] = fmaxf(acc, 0.f);
  }
  __syncthreads();
  if (j < 10) {
    float acc = bl[j];
#pragma unroll
    for (int k = 0; k < 20; ++k) acc = fmaf(s_b[k], Wl[k * 10 + j], acc);
    out[j] = acc;
  }
}

extern "C" void kernel_launch(void* const* d_in, const int* in_sizes, int n_in,
                              void* d_out, int out_size, void* d_ws, size_t ws_size,
                              hipStream_t stream) {
  const float* x   = (const float*)d_in[0];
  const float* W1  = (const float*)d_in[1];
  const float* U1  = (const float*)d_in[2];
  const float* b1  = (const float*)d_in[3];
  const float* W2  = (const float*)d_in[4];
  const float* U2  = (const float*)d_in[5];
  const float* b2  = (const float*)d_in[6];
  const float* W3  = (const float*)d_in[7];
  const float* U3  = (const float*)d_in[8];
  const float* b3  = (const float*)d_in[9];
  const float* Wd1 = (const float*)d_in[10];
  const float* bd1 = (const float*)d_in[11];
  const float* Wd2 = (const float*)d_in[12];
  const float* bd2 = (const float*)d_in[13];
  const float* Wl  = (const float*)d_in[14];
  const float* bl  = (const float*)d_in[15];
  const int T = in_sizes[0] / 2;  // 16384

  // workspace: xw [T,256] | h3 [64]
  float* xw = (float*)d_ws;
  float* h3 = xw + (size_t)T * G4;

  proj_x<<<T, G4, 0, stream>>>(x, W1, b1, xw);
  fused_scan<<<1, 768, 0, stream>>>(xw, U1, W2, U2, b2, W3, U3, b3, h3, T);
  head_k<<<1, 64, 0, stream>>>(h3, Wd1, bd1, Wd2, bd2, Wl, bl, (float*)d_out);
}